// Round 1
// baseline (133.520 us; speedup 1.0000x reference)
//
#include <hip/hip_runtime.h>
#include <cmath>

// Problem constants (from reference): F=2048, HOP=N=1024, B=8, T=2^20
#define BATCH   8
#define TLEN    1048576
#define NFRM    1025                 // frames per batch row
#define MROWS   (BATCH * NFRM)       // 8200 GEMM rows
#define MPAD    8320                 // 65 * 128 (padded rows in ws)
#define NDIM    1024                 // output coeffs per frame
#define KDIM    1024                 // folded frame length

typedef __attribute__((ext_vector_type(8))) _Float16 half8;
typedef __attribute__((ext_vector_type(4))) float    f32x4;

__device__ __forceinline__ unsigned short f2h(float f) {
    union { _Float16 h; unsigned short s; } v;
    v.h = (_Float16)f;   // RNE conversion
    return v.s;
}

// ---------------------------------------------------------------------------
// Kernel 1: generate the (symmetric) scaled DCT-IV matrix in fp16.
// C4[p][k] = cos(pi*(2p+1)(2k+1)/4096) * sqrt(2/1024)
// ---------------------------------------------------------------------------
__global__ __launch_bounds__(256) void c4gen_kernel(unsigned short* __restrict__ c4) {
    int idx = blockIdx.x * 256 + threadIdx.x;
    int p = idx >> 10;
    int k = idx & 1023;
    int m = ((2 * p + 1) * (2 * k + 1)) & 8191;  // mod 8192 (cos period)
    float v = cospif((float)m * (1.0f / 4096.0f)) * 0.04419417382415922f;
    c4[idx] = f2h(v);
}

// ---------------------------------------------------------------------------
// Kernel 2: MDCT fold.  Frame t of batch b covers x[(t-1)*1024 + n], n in
// [0,2048) (zero outside [0,T)).  Folded (y[n] = w[n]*x[..n]):
//   p in [0,512):    u[p] = -( y[1535-p] + y[1536+p] )
//   p in [512,1024): u[p] =    y[p-512]  - y[1535-p]
// Rows >= 8200 (tile padding) are zeroed.
// ---------------------------------------------------------------------------
__global__ __launch_bounds__(256) void fold_kernel(const float* __restrict__ x,
                                                   const float* __restrict__ w,
                                                   unsigned short* __restrict__ u) {
    int idx = blockIdx.x * 256 + threadIdx.x;
    int row = idx >> 10;
    int p   = idx & 1023;
    unsigned short val = 0;
    if (row < MROWS) {
        int b = row / NFRM;
        int t = row - b * NFRM;
        int off = (t - 1) * 1024;               // frame n -> x index off+n
        const float* xb = x + b * TLEN;
        float uu;
        if (p < 512) {
            int n1 = 1535 - p, n2 = 1536 + p;
            int i1 = off + n1, i2 = off + n2;
            float x1 = ((unsigned)i1 < (unsigned)TLEN) ? xb[i1] : 0.0f;
            float x2 = ((unsigned)i2 < (unsigned)TLEN) ? xb[i2] : 0.0f;
            uu = -(w[n1] * x1 + w[n2] * x2);
        } else {
            int n1 = p - 512, n2 = 1535 - p;
            int i1 = off + n1, i2 = off + n2;
            float x1 = ((unsigned)i1 < (unsigned)TLEN) ? xb[i1] : 0.0f;
            float x2 = ((unsigned)i2 < (unsigned)TLEN) ? xb[i2] : 0.0f;
            uu = w[n1] * x1 - w[n2] * x2;
        }
        val = f2h(uu);
    }
    u[idx] = val;
}

// ---------------------------------------------------------------------------
// Kernel 3: out[8200 x 1024] = u[8320 x 1024] @ C4[1024 x 1024], f16 MFMA.
// 128x128 block tile, BK=32, 4 waves each computing a 64x64 sub-tile as
// 4x4 grid of 16x16x32 MFMAs.  LDS rows padded to 40 halfs (80 B) to break
// power-of-2 bank strides.
// Fragment layouts (HW-verified per guide):
//   A: m = lane&15, k = (lane>>4)*8 + j   (8 contiguous k -> ds_read_b128)
//   B: n = lane&15, k = (lane>>4)*8 + j   (store B as [n][k], C4 symmetric)
//   C: col = lane&15, row = (lane>>4)*4 + reg
// ---------------------------------------------------------------------------
__global__ __launch_bounds__(256, 2)
void mdct_gemm(const unsigned short* __restrict__ u,
               const unsigned short* __restrict__ c4,
               float* __restrict__ out) {
    __shared__ unsigned short As[128 * 40];
    __shared__ unsigned short Bs[128 * 40];

    const int m0 = blockIdx.x * 128;
    const int n0 = blockIdx.y * 128;
    const int tid  = threadIdx.x;
    const int lane = tid & 63;
    const int wv   = tid >> 6;
    const int wm   = wv & 1;          // wave m-half
    const int wn   = wv >> 1;         // wave n-half
    const int m16  = lane & 15;
    const int quad = lane >> 4;

    f32x4 acc[4][4] = {};

    // staging: 256 threads, each stages 2 x 16B for A and 2 x 16B for B
    const int srow = tid >> 2;        // 0..63
    const int scu  = tid & 3;         // 16B unit within 32-half row

    for (int k0 = 0; k0 < KDIM; k0 += 32) {
        __syncthreads();
        {
            const uint4* gA0 = (const uint4*)(u  + (m0 + srow)      * KDIM + k0) + scu;
            const uint4* gA1 = (const uint4*)(u  + (m0 + srow + 64) * KDIM + k0) + scu;
            const uint4* gB0 = (const uint4*)(c4 + (n0 + srow)      * KDIM + k0) + scu;
            const uint4* gB1 = (const uint4*)(c4 + (n0 + srow + 64) * KDIM + k0) + scu;
            *(uint4*)&As[srow * 40 + scu * 8]        = *gA0;
            *(uint4*)&As[(srow + 64) * 40 + scu * 8] = *gA1;
            *(uint4*)&Bs[srow * 40 + scu * 8]        = *gB0;
            *(uint4*)&Bs[(srow + 64) * 40 + scu * 8] = *gB1;
        }
        __syncthreads();

        half8 af[4], bf[4];
#pragma unroll
        for (int i = 0; i < 4; ++i) {
            af[i] = *(const half8*)&As[(wm * 64 + i * 16 + m16) * 40 + quad * 8];
            bf[i] = *(const half8*)&Bs[(wn * 64 + i * 16 + m16) * 40 + quad * 8];
        }
#pragma unroll
        for (int mi = 0; mi < 4; ++mi)
#pragma unroll
            for (int ni = 0; ni < 4; ++ni)
                acc[mi][ni] = __builtin_amdgcn_mfma_f32_16x16x32_f16(
                    af[mi], bf[ni], acc[mi][ni], 0, 0, 0);
    }

    // epilogue
    const int colb = n0 + wn * 64 + m16;
    const int rowb = m0 + wm * 64 + quad * 4;
    const bool full = (m0 + 128 <= MROWS);
#pragma unroll
    for (int mi = 0; mi < 4; ++mi) {
#pragma unroll
        for (int ni = 0; ni < 4; ++ni) {
#pragma unroll
            for (int j = 0; j < 4; ++j) {
                int r = rowb + mi * 16 + j;
                if (full || r < MROWS)
                    out[r * NDIM + colb + ni * 16] = acc[mi][ni][j];
            }
        }
    }
}

// ---------------------------------------------------------------------------
extern "C" void kernel_launch(void* const* d_in, const int* in_sizes, int n_in,
                              void* d_out, int out_size, void* d_ws, size_t ws_size,
                              hipStream_t stream) {
    const float* x = (const float*)d_in[0];   // (8, 1048576) fp32
    const float* w = (const float*)d_in[1];   // (2048,) fp32
    float* out = (float*)d_out;               // (8, 1025, 1024) fp32

    unsigned short* c4 = (unsigned short*)d_ws;          // 1024*1024 f16 (2 MB)
    unsigned short* u  = c4 + 1024 * 1024;               // 8320*1024 f16 (17 MB)

    c4gen_kernel<<<(1024 * 1024) / 256, 256, 0, stream>>>(c4);
    fold_kernel<<<(MPAD * 1024) / 256, 256, 0, stream>>>(x, w, u);
    dim3 grid(MPAD / 128, NDIM / 128);
    mdct_gemm<<<grid, 256, 0, stream>>>(u, c4, out);
}

// Round 2
// 122.529 us; speedup vs baseline: 1.0897x; 1.0897x over previous
//
#include <hip/hip_runtime.h>
#include <cmath>

// Problem constants: F=2048, HOP=N=1024, B=8, T=2^20
#define BATCH   8
#define TLEN    1048576
#define NFRM    1025                 // frames per batch row
#define MROWS   (BATCH * NFRM)       // 8200 GEMM rows
#define MPAD    8320                 // 65 * 128
#define NDIM    1024
#define KDIM    1024

typedef __attribute__((ext_vector_type(8))) _Float16 half8;
typedef __attribute__((ext_vector_type(4))) float    f32x4;

__device__ __forceinline__ unsigned short f2h(float f) {
    union { _Float16 h; unsigned short s; } v;
    v.h = (_Float16)f;
    return v.s;
}

// async global->LDS, 16B per lane; LDS dest = wave-uniform base + lane*16
__device__ __forceinline__ void gl_lds16(const void* g, void* l) {
    __builtin_amdgcn_global_load_lds(
        (const __attribute__((address_space(1))) void*)(unsigned long long)(uintptr_t)g,
        (__attribute__((address_space(3))) void*)(unsigned int)(uintptr_t)l,
        16, 0, 0);
}

// ---------------------------------------------------------------------------
// Kernel 1: scaled DCT-IV matrix in fp16, 4 values/thread.
// C4[p][k] = cos(pi*(2p+1)(2k+1)/4096) * sqrt(2/1024)
// ---------------------------------------------------------------------------
__global__ __launch_bounds__(256) void c4gen_kernel(ushort4* __restrict__ c4) {
    int idx  = blockIdx.x * 256 + threadIdx.x;
    int base = idx * 4;
    int p = base >> 10;
    int k = base & 1023;
    int a = 2 * p + 1;
    int m0 = a * (2 * k + 1);
    ushort4 v;
    v.x = f2h(cospif((float)((m0        ) & 8191) * (1.0f / 4096.0f)) * 0.04419417382415922f);
    v.y = f2h(cospif((float)((m0 + 2 * a) & 8191) * (1.0f / 4096.0f)) * 0.04419417382415922f);
    v.z = f2h(cospif((float)((m0 + 4 * a) & 8191) * (1.0f / 4096.0f)) * 0.04419417382415922f);
    v.w = f2h(cospif((float)((m0 + 6 * a) & 8191) * (1.0f / 4096.0f)) * 0.04419417382415922f);
    c4[idx] = v;
}

// ---------------------------------------------------------------------------
// Kernel 2: MDCT fold, one block per (padded) frame row, 4 outputs/thread via
// float4 loads.  y[n] = w[n]*x[off+n], off=(t-1)*1024:
//   p in [0,512):    u[p] = -( y[1535-p] + y[1536+p] )   (all-valid unless t==1024)
//   p in [512,1024): u[p] =    y[p-512]  - y[1535-p]     (all-valid unless t==0)
// Edge frames zero exactly one half; interior loads are always in-bounds.
// ---------------------------------------------------------------------------
__global__ __launch_bounds__(256) void fold_kernel(const float* __restrict__ x,
                                                   const float* __restrict__ w,
                                                   ushort4* __restrict__ u) {
    const int r   = blockIdx.x;
    const int tid = threadIdx.x;
    const int p   = tid * 4;
    ushort4 val = {0, 0, 0, 0};
    if (r < MROWS) {
        const int b = r / NFRM;
        const int t = r - b * NFRM;
        const float* xb = x + b * TLEN + (t - 1) * 1024;
        const bool low = (p < 512);
        const bool valid = low ? (t != NFRM - 1) : (t != 0);
        if (valid) {
            float4 xr, wr, xf, wf, res;
            const int rb = 1532 - p;                  // reversed base
            const int fb = low ? (1536 + p) : (p - 512);
            xr = *(const float4*)(xb + rb);
            wr = *(const float4*)(w  + rb);
            xf = *(const float4*)(xb + fb);
            wf = *(const float4*)(w  + fb);
            if (low) {
                res.x = -(wr.w * xr.w + wf.x * xf.x);
                res.y = -(wr.z * xr.z + wf.y * xf.y);
                res.z = -(wr.y * xr.y + wf.z * xf.z);
                res.w = -(wr.x * xr.x + wf.w * xf.w);
            } else {
                res.x = wf.x * xf.x - wr.w * xr.w;
                res.y = wf.y * xf.y - wr.z * xr.z;
                res.z = wf.z * xf.z - wr.y * xr.y;
                res.w = wf.w * xf.w - wr.x * xr.x;
            }
            val.x = f2h(res.x); val.y = f2h(res.y);
            val.z = f2h(res.z); val.w = f2h(res.w);
        }
    }
    u[r * 256 + tid] = val;
}

// ---------------------------------------------------------------------------
// Kernel 3: out[8200 x 1024] = u[8320 x 1024] @ C4[1024 x 1024], f16 MFMA.
// 128x128 tile, BK=32, global_load_lds width-16 staging (m97 structure).
// LDS rows are 32 halfs (64 B), UNPADDED — required by global_load_lds's
// wave-uniform-base + lane*16 dest rule.  Each wave stages rows
// [wv*32, wv*32+32) of both tiles (2 chunks of 1 KB each per matrix).
// Fragment layouts: A/B: m|n = lane&15, k = (lane>>4)*8 + j;
// C: col = lane&15, row = (lane>>4)*4 + reg.
// ---------------------------------------------------------------------------
__global__ __launch_bounds__(256, 2)
void mdct_gemm(const unsigned short* __restrict__ u,
               const unsigned short* __restrict__ c4,
               float* __restrict__ out) {
    __shared__ unsigned short As[128 * 32];
    __shared__ unsigned short Bs[128 * 32];

    const int m0 = blockIdx.x * 128;
    const int n0 = blockIdx.y * 128;
    const int tid  = threadIdx.x;
    const int lane = tid & 63;
    const int wv   = tid >> 6;
    const int wm   = wv & 1;
    const int wn   = wv >> 1;
    const int m16  = lane & 15;
    const int quad = lane >> 4;

    f32x4 acc[4][4] = {};

    // staging addresses: lane L covers row (wv*32 + L/4), 16B-chunk (L%4)
    const int lrow = lane >> 2;
    const int lcol = lane & 3;
    const unsigned short* gA = u  + (m0 + wv * 32 + lrow) * KDIM + lcol * 8;
    const unsigned short* gB = c4 + (n0 + wv * 32 + lrow) * KDIM + lcol * 8;
    unsigned short* lA = As + wv * 1024;   // wave chunk base (elements)
    unsigned short* lB = Bs + wv * 1024;

    for (int k0 = 0; k0 < KDIM; k0 += 32) {
        __syncthreads();
        gl_lds16(gA + k0,             lA);
        gl_lds16(gA + k0 + 16 * KDIM, lA + 512);
        gl_lds16(gB + k0,             lB);
        gl_lds16(gB + k0 + 16 * KDIM, lB + 512);
        __syncthreads();

        half8 af[4], bf[4];
#pragma unroll
        for (int i = 0; i < 4; ++i) {
            af[i] = *(const half8*)&As[(wm * 64 + i * 16 + m16) * 32 + quad * 8];
            bf[i] = *(const half8*)&Bs[(wn * 64 + i * 16 + m16) * 32 + quad * 8];
        }
#pragma unroll
        for (int mi = 0; mi < 4; ++mi)
#pragma unroll
            for (int ni = 0; ni < 4; ++ni)
                acc[mi][ni] = __builtin_amdgcn_mfma_f32_16x16x32_f16(
                    af[mi], bf[ni], acc[mi][ni], 0, 0, 0);
    }

    const int colb = n0 + wn * 64 + m16;
    const int rowb = m0 + wm * 64 + quad * 4;
    const bool full = (m0 + 128 <= MROWS);
#pragma unroll
    for (int mi = 0; mi < 4; ++mi) {
#pragma unroll
        for (int ni = 0; ni < 4; ++ni) {
#pragma unroll
            for (int j = 0; j < 4; ++j) {
                int r = rowb + mi * 16 + j;
                if (full || r < MROWS)
                    out[r * NDIM + colb + ni * 16] = acc[mi][ni][j];
            }
        }
    }
}

// ---------------------------------------------------------------------------
extern "C" void kernel_launch(void* const* d_in, const int* in_sizes, int n_in,
                              void* d_out, int out_size, void* d_ws, size_t ws_size,
                              hipStream_t stream) {
    const float* x = (const float*)d_in[0];   // (8, 1048576) fp32
    const float* w = (const float*)d_in[1];   // (2048,) fp32
    float* out = (float*)d_out;               // (8, 1025, 1024) fp32

    unsigned short* c4 = (unsigned short*)d_ws;          // 1024*1024 f16 (2 MB)
    unsigned short* u  = c4 + 1024 * 1024;               // 8320*1024 f16 (17 MB)

    c4gen_kernel<<<1024, 256, 0, stream>>>((ushort4*)c4);
    fold_kernel<<<MPAD, 256, 0, stream>>>(x, w, (ushort4*)u);
    dim3 grid(MPAD / 128, NDIM / 128);
    mdct_gemm<<<grid, 256, 0, stream>>>(u, c4, out);
}

// Round 3
// 121.433 us; speedup vs baseline: 1.0995x; 1.0090x over previous
//
#include <hip/hip_runtime.h>
#include <cmath>

// Problem constants: F=2048, HOP=N=1024, B=8, T=2^20
#define BATCH   8
#define TLEN    1048576
#define NFRM    1025                 // frames per batch row
#define MROWS   (BATCH * NFRM)       // 8200 GEMM rows
#define MPAD    8320                 // 65 * 128
#define NDIM    1024
#define KDIM    1024

typedef __attribute__((ext_vector_type(8))) _Float16 half8;
typedef __attribute__((ext_vector_type(4))) float    f32x4;

__device__ __forceinline__ unsigned short f2h(float f) {
    union { _Float16 h; unsigned short s; } v;
    v.h = (_Float16)f;
    return v.s;
}

// async global->LDS, 16B per lane; LDS dest = wave-uniform base + lane*16
__device__ __forceinline__ void gl_lds16(const void* g, void* l) {
    __builtin_amdgcn_global_load_lds(
        (const __attribute__((address_space(1))) void*)(unsigned long long)(uintptr_t)g,
        (__attribute__((address_space(3))) void*)(unsigned int)(uintptr_t)l,
        16, 0, 0);
}

// ---------------------------------------------------------------------------
// Kernel 1 (fused prep): blocks [0,1024) generate the scaled DCT-IV matrix
// C4[p][k] = cos(pi*(2p+1)(2k+1)/4096) * sqrt(2/1024) in fp16 (4 vals/thread);
// blocks [1024, 1024+MPAD) do the MDCT fold for row r = blockIdx.x - 1024.
//
// Fold: y[n] = w[n]*x[off+n], off=(t-1)*1024:
//   p in [0,512):    u[p] = -( y[1535-p] + y[1536+p] )   (zero iff t==1024)
//   p in [512,1024): u[p] =    y[p-512]  - y[1535-p]     (zero iff t==0)
// Interior frames' loads are always in-bounds; edge frames zero one half.
// ---------------------------------------------------------------------------
__global__ __launch_bounds__(256) void prep_kernel(const float* __restrict__ x,
                                                   const float* __restrict__ w,
                                                   ushort4* __restrict__ u,
                                                   ushort4* __restrict__ c4) {
    const int blk = blockIdx.x;
    const int tid = threadIdx.x;
    if (blk < 1024) {
        // ---- C4 generation ----
        int idx  = blk * 256 + tid;
        int base = idx * 4;
        int p = base >> 10;
        int k = base & 1023;
        int a = 2 * p + 1;
        int m0 = a * (2 * k + 1);
        ushort4 v;
        v.x = f2h(cospif((float)((m0        ) & 8191) * (1.0f / 4096.0f)) * 0.04419417382415922f);
        v.y = f2h(cospif((float)((m0 + 2 * a) & 8191) * (1.0f / 4096.0f)) * 0.04419417382415922f);
        v.z = f2h(cospif((float)((m0 + 4 * a) & 8191) * (1.0f / 4096.0f)) * 0.04419417382415922f);
        v.w = f2h(cospif((float)((m0 + 6 * a) & 8191) * (1.0f / 4096.0f)) * 0.04419417382415922f);
        c4[idx] = v;
        return;
    }
    // ---- fold ----
    const int r = blk - 1024;
    const int p = tid * 4;
    ushort4 val = {0, 0, 0, 0};
    if (r < MROWS) {
        const int b = r / NFRM;
        const int t = r - b * NFRM;
        const float* xb = x + b * TLEN + (t - 1) * 1024;
        const bool low = (p < 512);
        const bool valid = low ? (t != NFRM - 1) : (t != 0);
        if (valid) {
            float4 xr, wr, xf, wf, res;
            const int rb = 1532 - p;                  // reversed base
            const int fb = low ? (1536 + p) : (p - 512);
            xr = *(const float4*)(xb + rb);
            wr = *(const float4*)(w  + rb);
            xf = *(const float4*)(xb + fb);
            wf = *(const float4*)(w  + fb);
            if (low) {
                res.x = -(wr.w * xr.w + wf.x * xf.x);
                res.y = -(wr.z * xr.z + wf.y * xf.y);
                res.z = -(wr.y * xr.y + wf.z * xf.z);
                res.w = -(wr.x * xr.x + wf.w * xf.w);
            } else {
                res.x = wf.x * xf.x - wr.w * xr.w;
                res.y = wf.y * xf.y - wr.z * xr.z;
                res.z = wf.z * xf.z - wr.y * xr.y;
                res.w = wf.w * xf.w - wr.x * xr.x;
            }
            val.x = f2h(res.x); val.y = f2h(res.y);
            val.z = f2h(res.z); val.w = f2h(res.w);
        }
    }
    u[r * 256 + tid] = val;
}

// ---------------------------------------------------------------------------
// Kernel 2: out[8200 x 1024] = u[8320 x 1024] @ C4[1024 x 1024], f16 MFMA.
// 128x128 tile, BK=64 as TWO side-by-side BK=32 sub-tiles (As[2], Bs[2]),
// each with 64-B unpadded rows (conflict-free fragment reads + legal
// global_load_lds wave-uniform dest).  Halves barrier count vs BK=32:
// one vmcnt(0) drain per 32 MFMAs instead of 16.
// Fragment layouts: A/B: m|n = lane&15, k = (lane>>4)*8 + j;
// C: col = lane&15, row = (lane>>4)*4 + reg.
// ---------------------------------------------------------------------------
__global__ __launch_bounds__(256, 2)
void mdct_gemm(const unsigned short* __restrict__ u,
               const unsigned short* __restrict__ c4,
               float* __restrict__ out) {
    __shared__ unsigned short As[2][128 * 32];
    __shared__ unsigned short Bs[2][128 * 32];

    const int m0 = blockIdx.x * 128;
    const int n0 = blockIdx.y * 128;
    const int tid  = threadIdx.x;
    const int lane = tid & 63;
    const int wv   = tid >> 6;
    const int wm   = wv & 1;
    const int wn   = wv >> 1;
    const int m16  = lane & 15;
    const int quad = lane >> 4;

    f32x4 acc[4][4] = {};

    // staging: lane L covers row (wv*32 + L/4), 16B chunk (L%4) of a sub-tile
    const int lrow = lane >> 2;
    const int lcol = lane & 3;
    const unsigned short* gA = u  + (m0 + wv * 32 + lrow) * KDIM + lcol * 8;
    const unsigned short* gB = c4 + (n0 + wv * 32 + lrow) * KDIM + lcol * 8;
    unsigned short* lA0 = &As[0][wv * 1024];
    unsigned short* lA1 = &As[1][wv * 1024];
    unsigned short* lB0 = &Bs[0][wv * 1024];
    unsigned short* lB1 = &Bs[1][wv * 1024];

    for (int k0 = 0; k0 < KDIM; k0 += 64) {
        __syncthreads();
        gl_lds16(gA + k0,                  lA0);
        gl_lds16(gA + k0      + 16 * KDIM, lA0 + 512);
        gl_lds16(gA + k0 + 32,             lA1);
        gl_lds16(gA + k0 + 32 + 16 * KDIM, lA1 + 512);
        gl_lds16(gB + k0,                  lB0);
        gl_lds16(gB + k0      + 16 * KDIM, lB0 + 512);
        gl_lds16(gB + k0 + 32,             lB1);
        gl_lds16(gB + k0 + 32 + 16 * KDIM, lB1 + 512);
        __syncthreads();

#pragma unroll
        for (int h = 0; h < 2; ++h) {
            half8 af[4], bf[4];
#pragma unroll
            for (int i = 0; i < 4; ++i) {
                af[i] = *(const half8*)&As[h][(wm * 64 + i * 16 + m16) * 32 + quad * 8];
                bf[i] = *(const half8*)&Bs[h][(wn * 64 + i * 16 + m16) * 32 + quad * 8];
            }
#pragma unroll
            for (int mi = 0; mi < 4; ++mi)
#pragma unroll
                for (int ni = 0; ni < 4; ++ni)
                    acc[mi][ni] = __builtin_amdgcn_mfma_f32_16x16x32_f16(
                        af[mi], bf[ni], acc[mi][ni], 0, 0, 0);
        }
    }

    const int colb = n0 + wn * 64 + m16;
    const int rowb = m0 + wm * 64 + quad * 4;
    const bool full = (m0 + 128 <= MROWS);
#pragma unroll
    for (int mi = 0; mi < 4; ++mi) {
#pragma unroll
        for (int ni = 0; ni < 4; ++ni) {
#pragma unroll
            for (int j = 0; j < 4; ++j) {
                int r = rowb + mi * 16 + j;
                if (full || r < MROWS)
                    out[r * NDIM + colb + ni * 16] = acc[mi][ni][j];
            }
        }
    }
}

// ---------------------------------------------------------------------------
extern "C" void kernel_launch(void* const* d_in, const int* in_sizes, int n_in,
                              void* d_out, int out_size, void* d_ws, size_t ws_size,
                              hipStream_t stream) {
    const float* x = (const float*)d_in[0];   // (8, 1048576) fp32
    const float* w = (const float*)d_in[1];   // (2048,) fp32
    float* out = (float*)d_out;               // (8, 1025, 1024) fp32

    unsigned short* c4 = (unsigned short*)d_ws;          // 1024*1024 f16 (2 MB)
    unsigned short* u  = c4 + 1024 * 1024;               // 8320*1024 f16 (17 MB)

    prep_kernel<<<1024 + MPAD, 256, 0, stream>>>(x, w, (ushort4*)u, (ushort4*)c4);
    dim3 grid(MPAD / 128, NDIM / 128);
    mdct_gemm<<<grid, 256, 0, stream>>>(u, c4, out);
}

// Round 4
// 119.395 us; speedup vs baseline: 1.1183x; 1.0171x over previous
//
#include <hip/hip_runtime.h>
#include <cmath>

// Problem constants: F=2048, HOP=N=1024, B=8, T=2^20
#define BATCH   8
#define TLEN    1048576
#define NFRM    1025                 // frames per batch row
#define MROWS   (BATCH * NFRM)       // 8200 GEMM rows
#define MPAD    8320                 // 65 * 128
#define NDIM    1024
#define KDIM    1024

typedef __attribute__((ext_vector_type(8))) _Float16 half8;
typedef __attribute__((ext_vector_type(4))) float    f32x4;

__device__ __forceinline__ unsigned short f2h(float f) {
    union { _Float16 h; unsigned short s; } v;
    v.h = (_Float16)f;
    return v.s;
}

// async global->LDS, 16B per lane; LDS dest = wave-uniform base + lane*16
__device__ __forceinline__ void gl_lds16(const void* g, void* l) {
    __builtin_amdgcn_global_load_lds(
        (const __attribute__((address_space(1))) void*)(unsigned long long)(uintptr_t)g,
        (__attribute__((address_space(3))) void*)(unsigned int)(uintptr_t)l,
        16, 0, 0);
}

// ---------------------------------------------------------------------------
// Kernel 1 (fused prep): blocks [0,1024) generate the scaled DCT-IV matrix
// C4[p][k] = cos(pi*(2p+1)(2k+1)/4096) * sqrt(2/1024) in fp16 (4 vals/thread);
// blocks [1024, 1024+MPAD) do the MDCT fold for row r = blockIdx.x - 1024.
//
// Fold: y[n] = w[n]*x[off+n], off=(t-1)*1024:
//   p in [0,512):    u[p] = -( y[1535-p] + y[1536+p] )   (zero iff t==1024)
//   p in [512,1024): u[p] =    y[p-512]  - y[1535-p]     (zero iff t==0)
// Interior frames' loads are always in-bounds; edge frames zero one half.
// ---------------------------------------------------------------------------
__global__ __launch_bounds__(256) void prep_kernel(const float* __restrict__ x,
                                                   const float* __restrict__ w,
                                                   ushort4* __restrict__ u,
                                                   ushort4* __restrict__ c4) {
    const int blk = blockIdx.x;
    const int tid = threadIdx.x;
    if (blk < 1024) {
        // ---- C4 generation ----
        int idx  = blk * 256 + tid;
        int base = idx * 4;
        int p = base >> 10;
        int k = base & 1023;
        int a = 2 * p + 1;
        int m0 = a * (2 * k + 1);
        ushort4 v;
        v.x = f2h(cospif((float)((m0        ) & 8191) * (1.0f / 4096.0f)) * 0.04419417382415922f);
        v.y = f2h(cospif((float)((m0 + 2 * a) & 8191) * (1.0f / 4096.0f)) * 0.04419417382415922f);
        v.z = f2h(cospif((float)((m0 + 4 * a) & 8191) * (1.0f / 4096.0f)) * 0.04419417382415922f);
        v.w = f2h(cospif((float)((m0 + 6 * a) & 8191) * (1.0f / 4096.0f)) * 0.04419417382415922f);
        c4[idx] = v;
        return;
    }
    // ---- fold ----
    const int r = blk - 1024;
    const int p = tid * 4;
    ushort4 val = {0, 0, 0, 0};
    if (r < MROWS) {
        const int b = r / NFRM;
        const int t = r - b * NFRM;
        const float* xb = x + b * TLEN + (t - 1) * 1024;
        const bool low = (p < 512);
        const bool valid = low ? (t != NFRM - 1) : (t != 0);
        if (valid) {
            float4 xr, wr, xf, wf, res;
            const int rb = 1532 - p;                  // reversed base
            const int fb = low ? (1536 + p) : (p - 512);
            xr = *(const float4*)(xb + rb);
            wr = *(const float4*)(w  + rb);
            xf = *(const float4*)(xb + fb);
            wf = *(const float4*)(w  + fb);
            if (low) {
                res.x = -(wr.w * xr.w + wf.x * xf.x);
                res.y = -(wr.z * xr.z + wf.y * xf.y);
                res.z = -(wr.y * xr.y + wf.z * xf.z);
                res.w = -(wr.x * xr.x + wf.w * xf.w);
            } else {
                res.x = wf.x * xf.x - wr.w * xr.w;
                res.y = wf.y * xf.y - wr.z * xr.z;
                res.z = wf.z * xf.z - wr.y * xr.y;
                res.w = wf.w * xf.w - wr.x * xr.x;
            }
            val.x = f2h(res.x); val.y = f2h(res.y);
            val.z = f2h(res.z); val.w = f2h(res.w);
        }
    }
    u[r * 256 + tid] = val;
}

// ---------------------------------------------------------------------------
// Kernel 2: out[8200 x 1024] = u[8320 x 1024] @ C4[1024 x 1024], f16 MFMA.
// 128x128 tile, BK=64 as two side-by-side BK=32 sub-tiles, global_load_lds
// width-16 staging, 64-B unpadded LDS rows.
// GRID IS N-FASTEST: blockIdx.x = n-tile (8), blockIdx.y = m-tile (65).
// The 8 concurrently-dispatched blocks of an m-group share one A-tile ->
// u fetched from HBM once (~17 MB total) instead of 8x; c4 (2 MB) is
// LLC-resident after the first group.  [R3 post-mortem: m-fastest grid
// fetched 75 MB and the gemm was HBM-fetch-bound at 2.55 TB/s.]
// Fragment layouts: A/B: m|n = lane&15, k = (lane>>4)*8 + j;
// C: col = lane&15, row = (lane>>4)*4 + reg.
// ---------------------------------------------------------------------------
__global__ __launch_bounds__(256, 2)
void mdct_gemm(const unsigned short* __restrict__ u,
               const unsigned short* __restrict__ c4,
               float* __restrict__ out) {
    __shared__ unsigned short As[2][128 * 32];
    __shared__ unsigned short Bs[2][128 * 32];

    const int m0 = blockIdx.y * 128;
    const int n0 = blockIdx.x * 128;
    const int tid  = threadIdx.x;
    const int lane = tid & 63;
    const int wv   = tid >> 6;
    const int wm   = wv & 1;
    const int wn   = wv >> 1;
    const int m16  = lane & 15;
    const int quad = lane >> 4;

    f32x4 acc[4][4] = {};

    // staging: lane L covers row (wv*32 + L/4), 16B chunk (L%4) of a sub-tile
    const int lrow = lane >> 2;
    const int lcol = lane & 3;
    const unsigned short* gA = u  + (m0 + wv * 32 + lrow) * KDIM + lcol * 8;
    const unsigned short* gB = c4 + (n0 + wv * 32 + lrow) * KDIM + lcol * 8;
    unsigned short* lA0 = &As[0][wv * 1024];
    unsigned short* lA1 = &As[1][wv * 1024];
    unsigned short* lB0 = &Bs[0][wv * 1024];
    unsigned short* lB1 = &Bs[1][wv * 1024];

    for (int k0 = 0; k0 < KDIM; k0 += 64) {
        __syncthreads();
        gl_lds16(gA + k0,                  lA0);
        gl_lds16(gA + k0      + 16 * KDIM, lA0 + 512);
        gl_lds16(gA + k0 + 32,             lA1);
        gl_lds16(gA + k0 + 32 + 16 * KDIM, lA1 + 512);
        gl_lds16(gB + k0,                  lB0);
        gl_lds16(gB + k0      + 16 * KDIM, lB0 + 512);
        gl_lds16(gB + k0 + 32,             lB1);
        gl_lds16(gB + k0 + 32 + 16 * KDIM, lB1 + 512);
        __syncthreads();

#pragma unroll
        for (int h = 0; h < 2; ++h) {
            half8 af[4], bf[4];
#pragma unroll
            for (int i = 0; i < 4; ++i) {
                af[i] = *(const half8*)&As[h][(wm * 64 + i * 16 + m16) * 32 + quad * 8];
                bf[i] = *(const half8*)&Bs[h][(wn * 64 + i * 16 + m16) * 32 + quad * 8];
            }
#pragma unroll
            for (int mi = 0; mi < 4; ++mi)
#pragma unroll
                for (int ni = 0; ni < 4; ++ni)
                    acc[mi][ni] = __builtin_amdgcn_mfma_f32_16x16x32_f16(
                        af[mi], bf[ni], acc[mi][ni], 0, 0, 0);
        }
    }

    const int colb = n0 + wn * 64 + m16;
    const int rowb = m0 + wm * 64 + quad * 4;
    const bool full = (m0 + 128 <= MROWS);
#pragma unroll
    for (int mi = 0; mi < 4; ++mi) {
#pragma unroll
        for (int ni = 0; ni < 4; ++ni) {
#pragma unroll
            for (int j = 0; j < 4; ++j) {
                int r = rowb + mi * 16 + j;
                if (full || r < MROWS)
                    out[r * NDIM + colb + ni * 16] = acc[mi][ni][j];
            }
        }
    }
}

// ---------------------------------------------------------------------------
extern "C" void kernel_launch(void* const* d_in, const int* in_sizes, int n_in,
                              void* d_out, int out_size, void* d_ws, size_t ws_size,
                              hipStream_t stream) {
    const float* x = (const float*)d_in[0];   // (8, 1048576) fp32
    const float* w = (const float*)d_in[1];   // (2048,) fp32
    float* out = (float*)d_out;               // (8, 1025, 1024) fp32

    unsigned short* c4 = (unsigned short*)d_ws;          // 1024*1024 f16 (2 MB)
    unsigned short* u  = c4 + 1024 * 1024;               // 8320*1024 f16 (17 MB)

    prep_kernel<<<1024 + MPAD, 256, 0, stream>>>(x, w, (ushort4*)u, (ushort4*)c4);
    dim3 grid(NDIM / 128, MPAD / 128);                   // x = n-tile (fast), y = m-tile
    mdct_gemm<<<grid, 256, 0, stream>>>(u, c4, out);
}